// Round 1
// baseline (547.932 us; speedup 1.0000x reference)
//
#include <hip/hip_runtime.h>
#include <hip/hip_bf16.h>
#include <cstdint>
#include <cstddef>

// Problem dims (fixed)
constexpr int B_SZ = 64, IC = 2048, IH = 16, OC = 64, OH = 32;
constexpr int NN = OC * OH;          // 2048 flattened (o,j)
constexpr int ICHUNK = 32;           // i's per block
constexpr int NCHUNK = IC / ICHUNK;  // 64
constexpr int BTILE = 16;            // b's per block

typedef __attribute__((ext_vector_type(8))) short bf16x8;
typedef __attribute__((ext_vector_type(4))) float f32x4;

// ---- LDS layout (bytes), dynamic shared ----
constexpr int Z_OFF = 0;                        // 16B zero pad region
constexpr int W_OFF = 64;
constexpr int WSLOT = 2048 * 8 * 2;             // 32768 B per k-octet slot
constexpr int V_OFF = W_OFF + 2 * WSLOT;        // 65600
constexpr int VO_STRIDE = 72;                   // bytes per o-row (32 bf16 + pad)
constexpr int VB_STRIDE = 4616;                 // bytes per b-row (64*72 + 8 pad)
constexpr int BL_OFF = V_OFF + 16 * VB_STRIDE;  // 139456
constexpr int BL_ROW = 68;                      // floats per Blog/C row (64 + pad)
constexpr int C_OFF = BL_OFF + 16 * BL_ROW * 4; // 143808
constexpr int SMEM_BYTES = C_OFF + 16 * BL_ROW * 4; // 148160 (< 160 KiB)

__device__ __forceinline__ unsigned short f2bf(float f) {
    unsigned u = __float_as_uint(f);
    u += 0x7fffu + ((u >> 16) & 1u);            // round-to-nearest-even
    return (unsigned short)(u >> 16);
}
__device__ __forceinline__ float bf2f(unsigned short h) {
    return __uint_as_float(((unsigned)h) << 16);
}
__device__ __forceinline__ unsigned pk2f(float a, float b) {
    return (unsigned)f2bf(a) | ((unsigned)f2bf(b) << 16);
}
__device__ __forceinline__ float dot4bf(f32x4 a, ushort4 v) {
    return a.x * bf2f(v.x) + a.y * bf2f(v.y) + a.z * bf2f(v.z) + a.w * bf2f(v.w);
}

// x [64][2048][16] f32 -> xs [2048][64][16] bf16
__global__ void prep_x(const float* __restrict__ x, unsigned short* __restrict__ xs) {
    int i = blockIdx.x;        // 0..2047
    int b = threadIdx.x;       // 0..63
    const float* p = x + ((size_t)b * IC + i) * IH;
    unsigned short out[16];
#pragma unroll
    for (int h = 0; h < 16; ++h) out[h] = f2bf(p[h]);
    unsigned short* q = xs + ((size_t)i * 64 + b) * 16;
    *(uint4*)q = *(uint4*)&out[0];
    *(uint4*)(q + 8) = *(uint4*)&out[8];
}

// One routing pass: computes per-(i-chunk) partial S into P[chunk][b][n].
// UNIFORM: C = 1/64 (first iteration). Otherwise Blog = U . Vin, C = softmax_o.
template <bool UNIFORM>
__launch_bounds__(512, 2)
__global__ void routed_pass(const unsigned short* __restrict__ xs,
                            const float* __restrict__ W,
                            const float* __restrict__ Vin,
                            float* __restrict__ P) {
    extern __shared__ char smem[];
    const int tid = threadIdx.x;
    const int lane = tid & 63;
    const int wv = tid >> 6;              // wave 0..7, owns o in [wv*8, wv*8+8)
    const int l15 = lane & 15;
    const int g = lane >> 4;              // lane group 0..3

    // block decode: 4 b-tiles of one chunk land on the same XCD (blockIdx % 8)
    const int v = blockIdx.x;
    const int bt = (v >> 3) & 3;
    const int chunk = (v & 7) + 8 * (v >> 5);
    const int b0 = bt * BTILE;
    const int i0 = chunk * ICHUNK;

    if (tid < 4) ((unsigned*)(smem + Z_OFF))[tid] = 0u;   // zero frag source

    if (!UNIFORM) {
        // stage V (per-b!) as bf16 into padded LDS: [16 b][64 o][32 j]
        int vb = tid >> 5, l32 = tid & 31;
        const float* vsrc = Vin + (size_t)(b0 + vb) * (OC * OH);
#pragma unroll
        for (int k2 = 0; k2 < 16; ++k2) {
            int q = l32 + 32 * k2;              // quad index 0..511
            int o = q >> 3, jq = (q & 7) * 4;
            float4 vv = *(const float4*)(vsrc + o * OH + jq);
            ushort4 pk;
            pk.x = f2bf(vv.x); pk.y = f2bf(vv.y); pk.z = f2bf(vv.z); pk.w = f2bf(vv.w);
            *(ushort4*)(smem + V_OFF + vb * VB_STRIDE + o * VO_STRIDE + jq * 2) = pk;
        }
    }

    const f32x4 fzero = {0.f, 0.f, 0.f, 0.f};
    f32x4 acc[16], sacc[16];
#pragma unroll
    for (int t = 0; t < 16; ++t) sacc[t] = fzero;

    for (int ii = 0; ii < ICHUNK; ++ii) {
        const int i = i0 + ii;
        __syncthreads();   // prev-iter LDS reads done (also covers preload visibility)

        // ---- stage W_i: fp32 [16 h][2048 n] -> LDS bf16 [slot=h>>3][n][e=h&7] ----
        {
            const float* wp = W + (size_t)i * (IH * NN);
#pragma unroll
            for (int k = 0; k < 4; ++k) {
                int n = tid + 512 * k;
                float h[16];
#pragma unroll
                for (int hh = 0; hh < 16; ++hh) h[hh] = wp[hh * NN + n];
                uint4 lo, hi;
                lo.x = pk2f(h[0], h[1]);  lo.y = pk2f(h[2], h[3]);
                lo.z = pk2f(h[4], h[5]);  lo.w = pk2f(h[6], h[7]);
                hi.x = pk2f(h[8], h[9]);  hi.y = pk2f(h[10], h[11]);
                hi.z = pk2f(h[12], h[13]); hi.w = pk2f(h[14], h[15]);
                *(uint4*)(smem + W_OFF + n * 16) = lo;
                *(uint4*)(smem + W_OFF + WSLOT + n * 16) = hi;
            }
        }
        __syncthreads();

        // ---- B operand: x fragment (B[k=h][col=b]); lanes>=32 are K-pad zeros ----
        bf16x8 xf = {0, 0, 0, 0, 0, 0, 0, 0};
        if (lane < 32) {
            const unsigned short* xp =
                xs + (size_t)i * 1024 + (size_t)(b0 + l15) * 16 + g * 8;
            xf = *(const bf16x8*)xp;
        }

        // ---- MFMA: D = W^T @ x^T = U^T; D[row=n-in-tile][col=b] ----
#pragma unroll
        for (int t = 0; t < 16; ++t) {
            int nt = (wv * 8 + (t >> 1)) * 32 + (t & 1) * 16;  // n-tile base
            const char* aptr = (lane < 32)
                ? (smem + W_OFF + g * WSLOT + (size_t)(nt + l15) * 16)
                : (smem + Z_OFF);
            bf16x8 af = *(const bf16x8*)aptr;
            acc[t] = __builtin_amdgcn_mfma_f32_16x16x32_bf16(af, xf, fzero, 0, 0, 0);
        }

        float c_o[8];
        if (UNIFORM) {
#pragma unroll
            for (int o8 = 0; o8 < 8; ++o8) c_o[o8] = 1.0f / 64.0f;
        } else {
            // ---- Blog[b][o] = sum_j U*V : j is lane-local (4 per reg quad) ----
#pragma unroll
            for (int o8 = 0; o8 < 8; ++o8) {
                int o = wv * 8 + o8;
                const char* vbase = smem + V_OFF + l15 * VB_STRIDE + o * VO_STRIDE;
                ushort4 va = *(const ushort4*)(vbase + g * 8);        // j = g*4..
                ushort4 vb2 = *(const ushort4*)(vbase + 32 + g * 8);  // j = 16+g*4..
                float p = dot4bf(acc[2 * o8], va) + dot4bf(acc[2 * o8 + 1], vb2);
                p += __shfl_xor(p, 16);
                p += __shfl_xor(p, 32);
                if (lane < 16) ((float*)(smem + BL_OFF))[l15 * BL_ROW + o] = p;
            }
            __syncthreads();
            // ---- softmax over o=64: wave handles 2 b-rows ----
            {
                int bb = 2 * wv + (lane >> 5);
                int o2 = lane & 31;
                float* BL = (float*)(smem + BL_OFF) + bb * BL_ROW;
                float v0 = BL[o2], v1 = BL[o2 + 32];
                float m = fmaxf(v0, v1);
#pragma unroll
                for (int d = 16; d >= 1; d >>= 1) m = fmaxf(m, __shfl_xor(m, d));
                float e0 = __expf(v0 - m), e1 = __expf(v1 - m);
                float s = e0 + e1;
#pragma unroll
                for (int d = 16; d >= 1; d >>= 1) s += __shfl_xor(s, d);
                float inv = 1.0f / s;
                float* CL = (float*)(smem + C_OFF) + bb * BL_ROW;
                CL[o2] = e0 * inv;
                CL[o2 + 32] = e1 * inv;
            }
            __syncthreads();
#pragma unroll
            for (int o8 = 0; o8 < 8; ++o8)
                c_o[o8] = ((const float*)(smem + C_OFF))[l15 * BL_ROW + wv * 8 + o8];
        }
        // ---- S += C * U ----
#pragma unroll
        for (int t = 0; t < 16; ++t) sacc[t] += acc[t] * c_o[t >> 1];
    }

    // ---- write partial S: P[chunk][b][n] ----
#pragma unroll
    for (int t = 0; t < 16; ++t) {
        int n = (wv * 8 + (t >> 1)) * 32 + (t & 1) * 16 + g * 4;
        float* dst = P + ((size_t)(chunk * 64) + b0 + l15) * NN + n;
        float4 o4;
        o4.x = sacc[t].x; o4.y = sacc[t].y; o4.z = sacc[t].z; o4.w = sacc[t].w;
        *(float4*)dst = o4;
    }
}

// Sum partials over chunks, squash over j, SET or ADD into dst.
__global__ void reduce_squash(const float* __restrict__ P, float* __restrict__ dst,
                              int addmode) {
    int pr = blockIdx.x * 2 + (threadIdx.x >> 5);  // (b,o) row 0..4095
    int j = threadIdx.x & 31;
    int b = pr >> 6, o = pr & 63;
    const float* p = P + (size_t)b * NN + o * 32 + j;
    float s = 0.f;
#pragma unroll 8
    for (int c = 0; c < NCHUNK; ++c) s += p[(size_t)c * (64 * NN)];
    float nsq = s * s;
#pragma unroll
    for (int d = 16; d >= 1; d >>= 1) nsq += __shfl_xor(nsq, d);
    float nrm = sqrtf(nsq);
    float f = nrm / (1.f + nsq);   // squash: x * ||x||/(1+||x||^2)
    float outv = s * f;
    int idx = pr * 32 + j;
    if (addmode) dst[idx] += outv;
    else dst[idx] = outv;
}

extern "C" void kernel_launch(void* const* d_in, const int* in_sizes, int n_in,
                              void* d_out, int out_size, void* d_ws, size_t ws_size,
                              hipStream_t stream) {
    const float* x = (const float*)d_in[0];   // [64][2048][16]
    const float* W = (const float*)d_in[1];   // [2048][16][64][32]
    float* out = (float*)d_out;               // [64][64][32]
    char* ws = (char*)d_ws;
    // ws layout: xs bf16 4 MiB | P f32 32 MiB | Vsum f32 512 KiB  (~36.5 MiB)
    unsigned short* xs = (unsigned short*)ws;
    float* P = (float*)(ws + ((size_t)4 << 20));
    float* Vsum = (float*)(ws + ((size_t)36 << 20));

    // allow >64 KiB dynamic LDS (no-op if not required on this runtime)
    (void)hipFuncSetAttribute(reinterpret_cast<const void*>(&routed_pass<true>),
                              hipFuncAttributeMaxDynamicSharedMemorySize, SMEM_BYTES);
    (void)hipFuncSetAttribute(reinterpret_cast<const void*>(&routed_pass<false>),
                              hipFuncAttributeMaxDynamicSharedMemorySize, SMEM_BYTES);

    prep_x<<<dim3(2048), dim3(64), 0, stream>>>(x, xs);
    // iter 1: uniform C -> S1 -> V1 (Vsum = V1)
    routed_pass<true><<<dim3(256), dim3(512), SMEM_BYTES, stream>>>(xs, W, nullptr, P);
    reduce_squash<<<dim3(2048), dim3(64), 0, stream>>>(P, Vsum, 0);
    // iter 2: Blog = U.V1 -> S2 -> V2 (Vsum = V1+V2)
    routed_pass<false><<<dim3(256), dim3(512), SMEM_BYTES, stream>>>(xs, W, Vsum, P);
    reduce_squash<<<dim3(2048), dim3(64), 0, stream>>>(P, Vsum, 1);
    // iter 3: Blog = U.(V1+V2) -> S3 -> V3 = output
    routed_pass<false><<<dim3(256), dim3(512), SMEM_BYTES, stream>>>(xs, W, Vsum, P);
    reduce_squash<<<dim3(2048), dim3(64), 0, stream>>>(P, out, 0);
}

// Round 2
// 385.967 us; speedup vs baseline: 1.4196x; 1.4196x over previous
//
#include <hip/hip_runtime.h>
#include <hip/hip_bf16.h>
#include <cstdint>
#include <cstddef>

// Problem dims (fixed)
constexpr int B_SZ = 64, IC = 2048, IH = 16, OC = 64, OH = 32;
constexpr int NN = OC * OH;          // 2048 flattened (o,j)
constexpr int ICHUNK = 32;           // i's per block
constexpr int NCHUNK = IC / ICHUNK;  // 64
constexpr int BTILE = 16;            // b's per block

typedef __attribute__((ext_vector_type(8))) short bf16x8;
typedef __attribute__((ext_vector_type(4))) float f32x4;

// ---------------- fast-path LDS layout (bytes) ----------------
constexpr int F_Z = 0;                      // 16B zeros (K-pad A-frag)
constexpr int F_W = 64;                     // double-buffered W: 2 x 64 KiB
constexpr int F_WBUF = 65536;               // [2 slot][2048 n][8 h] bf16 per i
constexpr int BL_ROW = 68;                  // floats per Blog/C row (64 + pad)
constexpr int F_BL = F_W + 2 * F_WBUF;      // 131136
constexpr int F_C = F_BL + 16 * BL_ROW * 4; // 135488
constexpr int F_SMEM = F_C + 16 * BL_ROW * 4; // 139840 (< 160 KiB)

// ---------------- fallback LDS layout (round-1, known-good) ----------------
constexpr int Z_OFF = 0;
constexpr int W_OFF = 64;
constexpr int WSLOT = 2048 * 8 * 2;
constexpr int V_OFF = W_OFF + 2 * WSLOT;
constexpr int VO_STRIDE = 72;
constexpr int VB_STRIDE = 4616;
constexpr int BL_OFF = V_OFF + 16 * VB_STRIDE;
constexpr int C_OFF = BL_OFF + 16 * BL_ROW * 4;
constexpr int SMEM_FB = C_OFF + 16 * BL_ROW * 4; // 148160

__device__ __forceinline__ unsigned short f2bf(float f) {
    unsigned u = __float_as_uint(f);
    u += 0x7fffu + ((u >> 16) & 1u);            // round-to-nearest-even
    return (unsigned short)(u >> 16);
}
__device__ __forceinline__ float bf2f(unsigned short h) {
    return __uint_as_float(((unsigned)h) << 16);
}
__device__ __forceinline__ unsigned pk2f(float a, float b) {
    return (unsigned)f2bf(a) | ((unsigned)f2bf(b) << 16);
}
__device__ __forceinline__ float dot4bf(f32x4 a, ushort4 v) {
    return a.x * bf2f(v.x) + a.y * bf2f(v.y) + a.z * bf2f(v.z) + a.w * bf2f(v.w);
}
__device__ __forceinline__ void gload_lds16(const void* g, void* l) {
    __builtin_amdgcn_global_load_lds(
        (const __attribute__((address_space(1))) void*)g,
        (__attribute__((address_space(3))) void*)l, 16, 0, 0);
}

// x [64][2048][16] f32 -> xs [2048][64][16] bf16
__global__ void prep_x(const float* __restrict__ x, unsigned short* __restrict__ xs) {
    int i = blockIdx.x;
    int b = threadIdx.x;
    const float* p = x + ((size_t)b * IC + i) * IH;
    unsigned short out[16];
#pragma unroll
    for (int h = 0; h < 16; ++h) out[h] = f2bf(p[h]);
    unsigned short* q = xs + ((size_t)i * 64 + b) * 16;
    *(uint4*)q = *(uint4*)&out[0];
    *(uint4*)(q + 8) = *(uint4*)&out[8];
}

// W fp32 [2048 i][16 h][2048 n] -> Wp bf16 [i][2 slot][2048 n][8 h]
// (exactly the LDS staging image; global_load_lds then copies it linearly)
__global__ void prep_w(const float* __restrict__ W, unsigned short* __restrict__ Wp) {
    int i = blockIdx.x;
    int t = threadIdx.x;            // 0..511, handles n = 4t..4t+3
    const float* wp = W + (size_t)i * (IH * NN);
    int n0 = t * 4;
    float4 row[16];
#pragma unroll
    for (int h = 0; h < 16; ++h) row[h] = *(const float4*)(wp + h * NN + n0);
    char* dst = (char*)Wp + (size_t)i * 65536;
#pragma unroll
    for (int q = 0; q < 4; ++q) {
        float v[16];
#pragma unroll
        for (int h = 0; h < 16; ++h) v[h] = ((const float*)&row[h])[q];
        uint4 lo, hi;
        lo.x = pk2f(v[0], v[1]);   lo.y = pk2f(v[2], v[3]);
        lo.z = pk2f(v[4], v[5]);   lo.w = pk2f(v[6], v[7]);
        hi.x = pk2f(v[8], v[9]);   hi.y = pk2f(v[10], v[11]);
        hi.z = pk2f(v[12], v[13]); hi.w = pk2f(v[14], v[15]);
        *(uint4*)(dst + (size_t)(n0 + q) * 16) = lo;
        *(uint4*)(dst + 32768 + (size_t)(n0 + q) * 16) = hi;
    }
}

// ---------------- fast routed pass ----------------
// Double-buffered global_load_lds staging of prepacked bf16 W, V in registers,
// raw s_barrier + counted vmcnt (loads for i+1 stay in flight across compute).
template <bool UNIFORM>
__launch_bounds__(512, 2)
__global__ void routed_fast(const unsigned short* __restrict__ xs,
                            const unsigned short* __restrict__ Wp,
                            const float* __restrict__ Vin,
                            float* __restrict__ P) {
    extern __shared__ char smem[];
    const int tid = threadIdx.x;
    const int lane = tid & 63;
    const int wv = tid >> 6;              // wave 0..7, owns o in [wv*8, wv*8+8)
    const int l15 = lane & 15;
    const int g = lane >> 4;

    const int v = blockIdx.x;
    const int bt = (v >> 3) & 3;          // 4 b-tiles of a chunk share an XCD
    const int chunk = (v & 7) + 8 * (v >> 5);
    const int b0 = bt * BTILE;
    const int i0 = chunk * ICHUNK;

    if (tid < 4) ((unsigned*)(smem + F_Z))[tid] = 0u;

    // V is i-invariant: load this lane's 64 needed values once.
    f32x4 vr0[8], vr1[8];
    if constexpr (!UNIFORM) {
#pragma unroll
        for (int o8 = 0; o8 < 8; ++o8) {
            const float* vb = Vin + ((size_t)(b0 + l15) * OC + (wv * 8 + o8)) * OH + g * 4;
            vr0[o8] = *(const f32x4*)vb;         // j = g*4..
            vr1[o8] = *(const f32x4*)(vb + 16);  // j = 16+g*4..
        }
    }

    // prologue: stage i0 into buf0; load x-frag for i0
    {
        const char* gs = (const char*)Wp + (size_t)i0 * 65536;
#pragma unroll
        for (int r = 0; r < 8; ++r) {
            int seg = r * 8 + wv;
            gload_lds16(gs + seg * 1024 + lane * 16, smem + F_W + seg * 1024);
        }
    }
    bf16x8 xf = {0, 0, 0, 0, 0, 0, 0, 0};
    if (lane < 32)
        xf = *(const bf16x8*)(xs + (size_t)i0 * 1024 + (size_t)(b0 + l15) * 16 + g * 8);

    const f32x4 fzero = {0.f, 0.f, 0.f, 0.f};
    f32x4 sacc[16];
#pragma unroll
    for (int t = 0; t < 16; ++t) sacc[t] = fzero;

    for (int ii = 0; ii < ICHUNK; ++ii) {
        const int cur = ii & 1, nxt = cur ^ 1;

        bf16x8 xf_n = {0, 0, 0, 0, 0, 0, 0, 0};
        if (ii + 1 < ICHUNK) {
            // issue next-i staging; it flies under this i's compute
            const char* gs = (const char*)Wp + (size_t)(i0 + ii + 1) * 65536;
            char* lb = smem + F_W + nxt * F_WBUF;
#pragma unroll
            for (int r = 0; r < 8; ++r) {
                int seg = r * 8 + wv;
                gload_lds16(gs + seg * 1024 + lane * 16, lb + seg * 1024);
            }
            if (lane < 32)
                xf_n = *(const bf16x8*)(xs + (size_t)(i0 + ii + 1) * 1024 +
                                        (size_t)(b0 + l15) * 16 + g * 8);
            // drain everything older than this iter's 9 new vmem ops
            asm volatile("s_waitcnt vmcnt(9)" ::: "memory");
        } else {
            asm volatile("s_waitcnt vmcnt(0)" ::: "memory");
        }
        __builtin_amdgcn_s_barrier();   // buf[cur] complete for all waves

        f32x4 acc[16];
        const char* wb = smem + F_W + cur * F_WBUF;
#pragma unroll
        for (int t = 0; t < 16; ++t) {
            int nt = (wv * 8 + (t >> 1)) * 32 + (t & 1) * 16;
            const char* aptr = (lane < 32)
                ? (wb + g * 32768 + (size_t)(nt + l15) * 16)
                : (smem + F_Z);
            bf16x8 af = *(const bf16x8*)aptr;
            acc[t] = __builtin_amdgcn_mfma_f32_16x16x32_bf16(af, xf, fzero, 0, 0, 0);
        }

        float c_o[8];
        if constexpr (UNIFORM) {
#pragma unroll
            for (int o8 = 0; o8 < 8; ++o8) c_o[o8] = 1.0f / 64.0f;
        } else {
            // Blog[b][o] = sum_j U*V with V in registers
#pragma unroll
            for (int o8 = 0; o8 < 8; ++o8) {
                f32x4 a0 = acc[2 * o8], a1 = acc[2 * o8 + 1];
                float p = a0.x * vr0[o8].x + a0.y * vr0[o8].y +
                          a0.z * vr0[o8].z + a0.w * vr0[o8].w +
                          a1.x * vr1[o8].x + a1.y * vr1[o8].y +
                          a1.z * vr1[o8].z + a1.w * vr1[o8].w;
                p += __shfl_xor(p, 16);
                p += __shfl_xor(p, 32);
                if (lane < 16) ((float*)(smem + F_BL))[l15 * BL_ROW + wv * 8 + o8] = p;
            }
            asm volatile("s_waitcnt lgkmcnt(0)" ::: "memory");
            __builtin_amdgcn_s_barrier();
            {
                int bb = 2 * wv + (lane >> 5);
                int o2 = lane & 31;
                float* BL = (float*)(smem + F_BL) + bb * BL_ROW;
                float v0 = BL[o2], v1 = BL[o2 + 32];
                float m = fmaxf(v0, v1);
#pragma unroll
                for (int d = 16; d >= 1; d >>= 1) m = fmaxf(m, __shfl_xor(m, d));
                float e0 = __expf(v0 - m), e1 = __expf(v1 - m);
                float s = e0 + e1;
#pragma unroll
                for (int d = 16; d >= 1; d >>= 1) s += __shfl_xor(s, d);
                float inv = 1.0f / s;
                float* CL = (float*)(smem + F_C) + bb * BL_ROW;
                CL[o2] = e0 * inv;
                CL[o2 + 32] = e1 * inv;
            }
            asm volatile("s_waitcnt lgkmcnt(0)" ::: "memory");
            __builtin_amdgcn_s_barrier();
            const float* CL = (const float*)(smem + F_C) + l15 * BL_ROW + wv * 8;
            f32x4 c01 = *(const f32x4*)CL;
            f32x4 c23 = *(const f32x4*)(CL + 4);
            c_o[0] = c01.x; c_o[1] = c01.y; c_o[2] = c01.z; c_o[3] = c01.w;
            c_o[4] = c23.x; c_o[5] = c23.y; c_o[6] = c23.z; c_o[7] = c23.w;
        }
#pragma unroll
        for (int t = 0; t < 16; ++t) sacc[t] += acc[t] * c_o[t >> 1];

        if constexpr (UNIFORM) {
            // ensure all waves' ds_reads of buf[cur] retired before it is restaged
            asm volatile("s_waitcnt lgkmcnt(0)" ::: "memory");
            __builtin_amdgcn_s_barrier();
        }
        xf = xf_n;
    }

    // write partial S: P[chunk][b][n]
#pragma unroll
    for (int t = 0; t < 16; ++t) {
        int n = (wv * 8 + (t >> 1)) * 32 + (t & 1) * 16 + g * 4;
        float* dst = P + ((size_t)(chunk * 64) + b0 + l15) * NN + n;
        float4 o4;
        o4.x = sacc[t].x; o4.y = sacc[t].y; o4.z = sacc[t].z; o4.w = sacc[t].w;
        *(float4*)dst = o4;
    }
}

// ---------------- fallback routed pass (round-1, known-good) ----------------
template <bool UNIFORM>
__launch_bounds__(512, 2)
__global__ void routed_pass(const unsigned short* __restrict__ xs,
                            const float* __restrict__ W,
                            const float* __restrict__ Vin,
                            float* __restrict__ P) {
    extern __shared__ char smem[];
    const int tid = threadIdx.x;
    const int lane = tid & 63;
    const int wv = tid >> 6;
    const int l15 = lane & 15;
    const int g = lane >> 4;

    const int v = blockIdx.x;
    const int bt = (v >> 3) & 3;
    const int chunk = (v & 7) + 8 * (v >> 5);
    const int b0 = bt * BTILE;
    const int i0 = chunk * ICHUNK;

    if (tid < 4) ((unsigned*)(smem + Z_OFF))[tid] = 0u;

    if (!UNIFORM) {
        int vb = tid >> 5, l32 = tid & 31;
        const float* vsrc = Vin + (size_t)(b0 + vb) * (OC * OH);
#pragma unroll
        for (int k2 = 0; k2 < 16; ++k2) {
            int q = l32 + 32 * k2;
            int o = q >> 3, jq = (q & 7) * 4;
            float4 vv = *(const float4*)(vsrc + o * OH + jq);
            ushort4 pk;
            pk.x = f2bf(vv.x); pk.y = f2bf(vv.y); pk.z = f2bf(vv.z); pk.w = f2bf(vv.w);
            *(ushort4*)(smem + V_OFF + vb * VB_STRIDE + o * VO_STRIDE + jq * 2) = pk;
        }
    }

    const f32x4 fzero = {0.f, 0.f, 0.f, 0.f};
    f32x4 acc[16], sacc[16];
#pragma unroll
    for (int t = 0; t < 16; ++t) sacc[t] = fzero;

    for (int ii = 0; ii < ICHUNK; ++ii) {
        const int i = i0 + ii;
        __syncthreads();
        {
            const float* wp = W + (size_t)i * (IH * NN);
#pragma unroll
            for (int k = 0; k < 4; ++k) {
                int n = tid + 512 * k;
                float h[16];
#pragma unroll
                for (int hh = 0; hh < 16; ++hh) h[hh] = wp[hh * NN + n];
                uint4 lo, hi;
                lo.x = pk2f(h[0], h[1]);  lo.y = pk2f(h[2], h[3]);
                lo.z = pk2f(h[4], h[5]);  lo.w = pk2f(h[6], h[7]);
                hi.x = pk2f(h[8], h[9]);  hi.y = pk2f(h[10], h[11]);
                hi.z = pk2f(h[12], h[13]); hi.w = pk2f(h[14], h[15]);
                *(uint4*)(smem + W_OFF + n * 16) = lo;
                *(uint4*)(smem + W_OFF + WSLOT + n * 16) = hi;
            }
        }
        __syncthreads();

        bf16x8 xf = {0, 0, 0, 0, 0, 0, 0, 0};
        if (lane < 32) {
            const unsigned short* xp =
                xs + (size_t)i * 1024 + (size_t)(b0 + l15) * 16 + g * 8;
            xf = *(const bf16x8*)xp;
        }

#pragma unroll
        for (int t = 0; t < 16; ++t) {
            int nt = (wv * 8 + (t >> 1)) * 32 + (t & 1) * 16;
            const char* aptr = (lane < 32)
                ? (smem + W_OFF + g * WSLOT + (size_t)(nt + l15) * 16)
                : (smem + Z_OFF);
            bf16x8 af = *(const bf16x8*)aptr;
            acc[t] = __builtin_amdgcn_mfma_f32_16x16x32_bf16(af, xf, fzero, 0, 0, 0);
        }

        float c_o[8];
        if (UNIFORM) {
#pragma unroll
            for (int o8 = 0; o8 < 8; ++o8) c_o[o8] = 1.0f / 64.0f;
        } else {
#pragma unroll
            for (int o8 = 0; o8 < 8; ++o8) {
                int o = wv * 8 + o8;
                const char* vbase = smem + V_OFF + l15 * VB_STRIDE + o * VO_STRIDE;
                ushort4 va = *(const ushort4*)(vbase + g * 8);
                ushort4 vb2 = *(const ushort4*)(vbase + 32 + g * 8);
                float p = dot4bf(acc[2 * o8], va) + dot4bf(acc[2 * o8 + 1], vb2);
                p += __shfl_xor(p, 16);
                p += __shfl_xor(p, 32);
                if (lane < 16) ((float*)(smem + BL_OFF))[l15 * BL_ROW + o] = p;
            }
            __syncthreads();
            {
                int bb = 2 * wv + (lane >> 5);
                int o2 = lane & 31;
                float* BL = (float*)(smem + BL_OFF) + bb * BL_ROW;
                float v0 = BL[o2], v1 = BL[o2 + 32];
                float m = fmaxf(v0, v1);
#pragma unroll
                for (int d = 16; d >= 1; d >>= 1) m = fmaxf(m, __shfl_xor(m, d));
                float e0 = __expf(v0 - m), e1 = __expf(v1 - m);
                float s = e0 + e1;
#pragma unroll
                for (int d = 16; d >= 1; d >>= 1) s += __shfl_xor(s, d);
                float inv = 1.0f / s;
                float* CL = (float*)(smem + C_OFF) + bb * BL_ROW;
                CL[o2] = e0 * inv;
                CL[o2 + 32] = e1 * inv;
            }
            __syncthreads();
#pragma unroll
            for (int o8 = 0; o8 < 8; ++o8)
                c_o[o8] = ((const float*)(smem + C_OFF))[l15 * BL_ROW + wv * 8 + o8];
        }
#pragma unroll
        for (int t = 0; t < 16; ++t) sacc[t] += acc[t] * c_o[t >> 1];
    }

#pragma unroll
    for (int t = 0; t < 16; ++t) {
        int n = (wv * 8 + (t >> 1)) * 32 + (t & 1) * 16 + g * 4;
        float* dst = P + ((size_t)(chunk * 64) + b0 + l15) * NN + n;
        float4 o4;
        o4.x = sacc[t].x; o4.y = sacc[t].y; o4.z = sacc[t].z; o4.w = sacc[t].w;
        *(float4*)dst = o4;
    }
}

// Sum partials over chunks, squash over j, SET or ADD into dst.
__global__ void reduce_squash(const float* __restrict__ P, float* __restrict__ dst,
                              int addmode) {
    int pr = blockIdx.x * 2 + (threadIdx.x >> 5);
    int j = threadIdx.x & 31;
    int b = pr >> 6, o = pr & 63;
    const float* p = P + (size_t)b * NN + o * 32 + j;
    float s = 0.f;
#pragma unroll 8
    for (int c = 0; c < NCHUNK; ++c) s += p[(size_t)c * (64 * NN)];
    float nsq = s * s;
#pragma unroll
    for (int d = 16; d >= 1; d >>= 1) nsq += __shfl_xor(nsq, d);
    float nrm = sqrtf(nsq);
    float f = nrm / (1.f + nsq);
    float outv = s * f;
    int idx = pr * 32 + j;
    if (addmode) dst[idx] += outv;
    else dst[idx] = outv;
}

extern "C" void kernel_launch(void* const* d_in, const int* in_sizes, int n_in,
                              void* d_out, int out_size, void* d_ws, size_t ws_size,
                              hipStream_t stream) {
    const float* x = (const float*)d_in[0];   // [64][2048][16]
    const float* W = (const float*)d_in[1];   // [2048][16][64][32]
    float* out = (float*)d_out;               // [64][64][32]
    char* ws = (char*)d_ws;
    // ws: xs bf16 4 MiB | P f32 32 MiB @4M | Vsum 512 KiB @36M | Wp bf16 128 MiB @40M
    unsigned short* xs = (unsigned short*)ws;
    float* P = (float*)(ws + ((size_t)4 << 20));
    float* Vsum = (float*)(ws + ((size_t)36 << 20));
    const size_t NEED = ((size_t)168) << 20;
    const bool fast = ws_size >= NEED;

    prep_x<<<dim3(2048), dim3(64), 0, stream>>>(x, xs);

    if (fast) {
        unsigned short* Wp = (unsigned short*)(ws + (((size_t)40) << 20));
        (void)hipFuncSetAttribute(reinterpret_cast<const void*>(&routed_fast<true>),
                                  hipFuncAttributeMaxDynamicSharedMemorySize, F_SMEM);
        (void)hipFuncSetAttribute(reinterpret_cast<const void*>(&routed_fast<false>),
                                  hipFuncAttributeMaxDynamicSharedMemorySize, F_SMEM);
        prep_w<<<dim3(2048), dim3(512), 0, stream>>>(W, Wp);
        routed_fast<true><<<dim3(256), dim3(512), F_SMEM, stream>>>(xs, Wp, nullptr, P);
        reduce_squash<<<dim3(2048), dim3(64), 0, stream>>>(P, Vsum, 0);
        routed_fast<false><<<dim3(256), dim3(512), F_SMEM, stream>>>(xs, Wp, Vsum, P);
        reduce_squash<<<dim3(2048), dim3(64), 0, stream>>>(P, Vsum, 1);
        routed_fast<false><<<dim3(256), dim3(512), F_SMEM, stream>>>(xs, Wp, Vsum, P);
        reduce_squash<<<dim3(2048), dim3(64), 0, stream>>>(P, out, 0);
    } else {
        (void)hipFuncSetAttribute(reinterpret_cast<const void*>(&routed_pass<true>),
                                  hipFuncAttributeMaxDynamicSharedMemorySize, SMEM_FB);
        (void)hipFuncSetAttribute(reinterpret_cast<const void*>(&routed_pass<false>),
                                  hipFuncAttributeMaxDynamicSharedMemorySize, SMEM_FB);
        routed_pass<true><<<dim3(256), dim3(512), SMEM_FB, stream>>>(xs, W, nullptr, P);
        reduce_squash<<<dim3(2048), dim3(64), 0, stream>>>(P, Vsum, 0);
        routed_pass<false><<<dim3(256), dim3(512), SMEM_FB, stream>>>(xs, W, Vsum, P);
        reduce_squash<<<dim3(2048), dim3(64), 0, stream>>>(P, Vsum, 1);
        routed_pass<false><<<dim3(256), dim3(512), SMEM_FB, stream>>>(xs, W, Vsum, P);
        reduce_squash<<<dim3(2048), dim3(64), 0, stream>>>(P, out, 0);
    }
}

// Round 3
// 351.662 us; speedup vs baseline: 1.5581x; 1.0976x over previous
//
#include <hip/hip_runtime.h>
#include <hip/hip_bf16.h>
#include <cstdint>
#include <cstddef>

// Problem dims (fixed)
constexpr int B_SZ = 64, IC = 2048, IH = 16, OC = 64, OH = 32;
constexpr int NN = OC * OH;          // 2048 flattened (o,j)
constexpr int ICHUNK = 32;           // i's per block
constexpr int NCHUNK = IC / ICHUNK;  // 64
constexpr int BTILE = 16;            // b's per block

typedef __attribute__((ext_vector_type(8))) short bf16x8;
typedef __attribute__((ext_vector_type(4))) float f32x4;

// ---- LDS layout (bytes), dynamic shared ----
constexpr int F_Z = 0;                        // 64 B zeros (K-pad A-frag)
constexpr int F_W = 64;                       // double-buffered W: 2 x 64 KiB
constexpr int F_WBUF = 65536;                 // [2 slot][2048 n][8 h] bf16 per i
constexpr int BL_ROW = 68;                    // floats per Blog/C row (64 + pad)
constexpr int F_BL = F_W + 2 * F_WBUF;        // 131136
constexpr int F_C = F_BL + 16 * BL_ROW * 4;   // 135488
constexpr int F_SMEM = F_C + 16 * BL_ROW * 4; // 139840 (< 160 KiB)

__device__ __forceinline__ unsigned short f2bf(float f) {
    unsigned u = __float_as_uint(f);
    u += 0x7fffu + ((u >> 16) & 1u);          // round-to-nearest-even
    return (unsigned short)(u >> 16);
}
__device__ __forceinline__ float bf_lo(unsigned u) {
    return __uint_as_float(u << 16);
}
__device__ __forceinline__ float bf_hi(unsigned u) {
    return __uint_as_float(u & 0xffff0000u);
}
__device__ __forceinline__ unsigned pk2f(float a, float b) {
    return (unsigned)f2bf(a) | ((unsigned)f2bf(b) << 16);
}
__device__ __forceinline__ void gload_lds16(const void* g, void* l) {
    __builtin_amdgcn_global_load_lds(
        (const __attribute__((address_space(1))) void*)g,
        (__attribute__((address_space(3))) void*)l, 16, 0, 0);
}

// Fused prep:
//   W fp32 [2048 i][16 h][2048 n] -> Wp bf16 [i][2 slot][2048 n][8 h]
//   x  f32 [64 b][2048 i][16 h]   -> xs bf16 [2048 i][64 b][16 h]   (threads 0..63)
__global__ void prep_wx(const float* __restrict__ W, unsigned short* __restrict__ Wp,
                        const float* __restrict__ x, unsigned short* __restrict__ xs) {
    int i = blockIdx.x;
    int t = threadIdx.x;            // 0..511, handles n = 4t..4t+3
    const float* wp = W + (size_t)i * (IH * NN);
    int n0 = t * 4;
    float4 row[16];
#pragma unroll
    for (int h = 0; h < 16; ++h) row[h] = *(const float4*)(wp + h * NN + n0);
    char* dst = (char*)Wp + (size_t)i * 65536;
#pragma unroll
    for (int q = 0; q < 4; ++q) {
        float v[16];
#pragma unroll
        for (int h = 0; h < 16; ++h) v[h] = ((const float*)&row[h])[q];
        uint4 lo, hi;
        lo.x = pk2f(v[0], v[1]);   lo.y = pk2f(v[2], v[3]);
        lo.z = pk2f(v[4], v[5]);   lo.w = pk2f(v[6], v[7]);
        hi.x = pk2f(v[8], v[9]);   hi.y = pk2f(v[10], v[11]);
        hi.z = pk2f(v[12], v[13]); hi.w = pk2f(v[14], v[15]);
        *(uint4*)(dst + (size_t)(n0 + q) * 16) = lo;
        *(uint4*)(dst + 32768 + (size_t)(n0 + q) * 16) = hi;
    }
    if (t < 64) {
        const float* p = x + ((size_t)t * IC + i) * IH;
        unsigned short out[16];
#pragma unroll
        for (int h = 0; h < 16; ++h) out[h] = f2bf(p[h]);
        unsigned short* q = xs + ((size_t)i * 64 + t) * 16;
        *(uint4*)q = *(uint4*)&out[0];
        *(uint4*)(q + 8) = *(uint4*)&out[8];
    }
}

// ---------------- routed pass: 16 waves, wave owns 4 o's ----------------
// Double-buffered global_load_lds staging of prepacked bf16 W; V packed bf16 in
// registers; UNIFORM accumulates in the MFMA C-operand (1 barrier/i); otherwise
// 2 barriers/i with the staging vmcnt folded into the C-ready barrier.
template <bool UNIFORM>
__launch_bounds__(1024, 4)
__global__ void routed_fast(const unsigned short* __restrict__ xs,
                            const unsigned short* __restrict__ Wp,
                            const float* __restrict__ Vin,
                            float* __restrict__ P) {
    extern __shared__ char smem[];
    const int tid = threadIdx.x;
    const int lane = tid & 63;
    const int wv = tid >> 6;              // wave 0..15, owns o in [wv*4, wv*4+4)
    const int l15 = lane & 15;
    const int g = lane >> 4;              // lane group 0..3

    const int v = blockIdx.x;
    const int bt = (v >> 3) & 3;          // 4 b-tiles of a chunk share an XCD
    const int chunk = (v & 7) + 8 * (v >> 5);
    const int b0 = bt * BTILE;
    const int i0 = chunk * ICHUNK;

    if (tid < 16) ((unsigned*)(smem + F_Z))[tid] = 0u;

    // V is i-invariant: this lane needs 32 values (4 o x 8 j); pack to bf16.
    uint4 vrp[4];
    if constexpr (!UNIFORM) {
#pragma unroll
        for (int o8 = 0; o8 < 4; ++o8) {
            const float* vb =
                Vin + ((size_t)(b0 + l15) * OC + (wv * 4 + o8)) * OH + g * 4;
            f32x4 a = *(const f32x4*)vb;          // j = g*4..
            f32x4 c = *(const f32x4*)(vb + 16);   // j = 16+g*4..
            vrp[o8].x = pk2f(a.x, a.y);
            vrp[o8].y = pk2f(a.z, a.w);
            vrp[o8].z = pk2f(c.x, c.y);
            vrp[o8].w = pk2f(c.z, c.w);
        }
    }

    // prologue: stage i0 into buf0
    {
        const char* gs = (const char*)Wp + (size_t)i0 * 65536;
#pragma unroll
        for (int r = 0; r < 4; ++r) {
            int seg = r * 16 + wv;
            gload_lds16(gs + seg * 1024 + lane * 16, smem + F_W + seg * 1024);
        }
    }
    asm volatile("s_waitcnt vmcnt(0)" ::: "memory");
    __builtin_amdgcn_s_barrier();

    const f32x4 fzero = {0.f, 0.f, 0.f, 0.f};
    f32x4 sacc[8];
#pragma unroll
    for (int t = 0; t < 8; ++t) sacc[t] = fzero;

    for (int ii = 0; ii < ICHUNK; ++ii) {
        const int cur = ii & 1;
        const char* wb = smem + F_W + cur * F_WBUF;
        const int i = i0 + ii;

        // x fragment for this i (B[k=h][col=b]); lanes>=32 are K-pad zeros
        bf16x8 xf = {0, 0, 0, 0, 0, 0, 0, 0};
        if (lane < 32)
            xf = *(const bf16x8*)(xs + (size_t)i * 1024 + (size_t)(b0 + l15) * 16 + g * 8);

        f32x4 acc[8];
#pragma unroll
        for (int t = 0; t < 8; ++t) {
            int nt = wv * 128 + (t >> 1) * 32 + (t & 1) * 16;
            const char* aptr = (lane < 32)
                ? (wb + g * 32768 + (size_t)(nt + l15) * 16)
                : (smem + F_Z);
            bf16x8 af = *(const bf16x8*)aptr;
            if constexpr (UNIFORM) {
                // accumulate directly: S_raw += U (scale by 1/64 at the end)
                sacc[t] = __builtin_amdgcn_mfma_f32_16x16x32_bf16(af, xf, sacc[t], 0, 0, 0);
            } else {
                acc[t] = __builtin_amdgcn_mfma_f32_16x16x32_bf16(af, xf, fzero, 0, 0, 0);
            }
        }

        // issue next-i staging; target buffer's last reads finished one
        // barrier ago, so this is safe, and the loads fly under softmax.
        if (ii + 1 < ICHUNK) {
            const char* gs = (const char*)Wp + (size_t)(i + 1) * 65536;
            char* lb = smem + F_W + (cur ^ 1) * F_WBUF;
#pragma unroll
            for (int r = 0; r < 4; ++r) {
                int seg = r * 16 + wv;
                gload_lds16(gs + seg * 1024 + lane * 16, lb + seg * 1024);
            }
        }

        if constexpr (UNIFORM) {
            // stage(i+1) complete + all waves past their reads of buf[cur]
            asm volatile("s_waitcnt vmcnt(0)" ::: "memory");
            __builtin_amdgcn_s_barrier();
        } else {
            // ---- Blog[b][o] = sum_j U*V (V packed bf16 in regs) ----
            float blf[4];
#pragma unroll
            for (int o8 = 0; o8 < 4; ++o8) {
                f32x4 a0 = acc[2 * o8], a1 = acc[2 * o8 + 1];
                uint4 u = vrp[o8];
                float p = a0.x * bf_lo(u.x) + a0.y * bf_hi(u.x) +
                          a0.z * bf_lo(u.y) + a0.w * bf_hi(u.y) +
                          a1.x * bf_lo(u.z) + a1.y * bf_hi(u.z) +
                          a1.z * bf_lo(u.w) + a1.w * bf_hi(u.w);
                p += __shfl_xor(p, 16);
                p += __shfl_xor(p, 32);
                blf[o8] = p;
            }
            if (lane < 16) {
                float4 b4;
                b4.x = blf[0]; b4.y = blf[1]; b4.z = blf[2]; b4.w = blf[3];
                *(float4*)((float*)(smem + F_BL) + l15 * BL_ROW + wv * 4) = b4;
            }
            asm volatile("s_waitcnt lgkmcnt(0)" ::: "memory");
            __builtin_amdgcn_s_barrier();              // BL ready

            // ---- softmax: wave wv handles b-row wv, full o in one wave ----
            {
                const float* BLr = (const float*)(smem + F_BL) + wv * BL_ROW;
                float xv = BLr[lane];
                float m = xv;
#pragma unroll
                for (int d = 32; d >= 1; d >>= 1) m = fmaxf(m, __shfl_xor(m, d));
                float e = __expf(xv - m);
                float s = e;
#pragma unroll
                for (int d = 32; d >= 1; d >>= 1) s += __shfl_xor(s, d);
                ((float*)(smem + F_C))[wv * BL_ROW + lane] = e * (1.0f / s);
            }
            asm volatile("s_waitcnt lgkmcnt(0)" ::: "memory");
            asm volatile("s_waitcnt vmcnt(0)" ::: "memory");   // stage(i+1) done
            __builtin_amdgcn_s_barrier();              // C ready + W ready

            float4 c4 = *(const float4*)((const float*)(smem + F_C) +
                                         l15 * BL_ROW + wv * 4);
#pragma unroll
            for (int t = 0; t < 8; ++t) {
                float c = (t < 2) ? c4.x : (t < 4) ? c4.y : (t < 6) ? c4.z : c4.w;
                sacc[t] += acc[t] * c;
            }
        }
    }

    // ---- write partial S: P[chunk][b][n] ----
    const float scale = UNIFORM ? (1.0f / 64.0f) : 1.0f;
#pragma unroll
    for (int t = 0; t < 8; ++t) {
        int n = wv * 128 + (t >> 1) * 32 + (t & 1) * 16 + g * 4;
        float* dst = P + ((size_t)(chunk * 64) + b0 + l15) * NN + n;
        float4 o4;
        o4.x = sacc[t].x * scale; o4.y = sacc[t].y * scale;
        o4.z = sacc[t].z * scale; o4.w = sacc[t].w * scale;
        *(float4*)dst = o4;
    }
}

// Sum partials over chunks, squash over j, SET or ADD into dst.
__global__ void reduce_squash(const float* __restrict__ P, float* __restrict__ dst,
                              int addmode) {
    int pr = blockIdx.x * 2 + (threadIdx.x >> 5);  // (b,o) row 0..4095
    int j = threadIdx.x & 31;
    int b = pr >> 6, o = pr & 63;
    const float* p = P + (size_t)b * NN + o * 32 + j;
    float s = 0.f;
#pragma unroll 8
    for (int c = 0; c < NCHUNK; ++c) s += p[(size_t)c * (64 * NN)];
    float nsq = s * s;
#pragma unroll
    for (int d = 16; d >= 1; d >>= 1) nsq += __shfl_xor(nsq, d);
    float nrm = sqrtf(nsq);
    float f = nrm / (1.f + nsq);   // squash: x * ||x||/(1+||x||^2)
    float outv = s * f;
    int idx = pr * 32 + j;
    if (addmode) dst[idx] += outv;
    else dst[idx] = outv;
}

extern "C" void kernel_launch(void* const* d_in, const int* in_sizes, int n_in,
                              void* d_out, int out_size, void* d_ws, size_t ws_size,
                              hipStream_t stream) {
    const float* x = (const float*)d_in[0];   // [64][2048][16]
    const float* W = (const float*)d_in[1];   // [2048][16][64][32]
    float* out = (float*)d_out;               // [64][64][32]
    char* ws = (char*)d_ws;
    // ws: xs bf16 4 MiB | P f32 32 MiB @4M | Vsum 512 KiB @36M | Wp bf16 128 MiB @40M
    unsigned short* xs = (unsigned short*)ws;
    float* P = (float*)(ws + ((size_t)4 << 20));
    float* Vsum = (float*)(ws + ((size_t)36 << 20));
    unsigned short* Wp = (unsigned short*)(ws + (((size_t)40) << 20));

    (void)hipFuncSetAttribute(reinterpret_cast<const void*>(&routed_fast<true>),
                              hipFuncAttributeMaxDynamicSharedMemorySize, F_SMEM);
    (void)hipFuncSetAttribute(reinterpret_cast<const void*>(&routed_fast<false>),
                              hipFuncAttributeMaxDynamicSharedMemorySize, F_SMEM);

    prep_wx<<<dim3(2048), dim3(512), 0, stream>>>(W, Wp, x, xs);
    // iter 1: uniform C -> S1 -> V1 (Vsum = V1)
    routed_fast<true><<<dim3(256), dim3(1024), F_SMEM, stream>>>(xs, Wp, nullptr, P);
    reduce_squash<<<dim3(2048), dim3(64), 0, stream>>>(P, Vsum, 0);
    // iter 2: Blog = U.V1 -> S2 -> V2 (Vsum = V1+V2)
    routed_fast<false><<<dim3(256), dim3(1024), F_SMEM, stream>>>(xs, Wp, Vsum, P);
    reduce_squash<<<dim3(2048), dim3(64), 0, stream>>>(P, Vsum, 1);
    // iter 3: Blog = U.(V1+V2) -> S3 -> V3 = output
    routed_fast<false><<<dim3(256), dim3(1024), F_SMEM, stream>>>(xs, Wp, Vsum, P);
    reduce_squash<<<dim3(2048), dim3(64), 0, stream>>>(P, out, 0);
}

// Round 4
// 323.001 us; speedup vs baseline: 1.6964x; 1.0887x over previous
//
#include <hip/hip_runtime.h>
#include <hip/hip_bf16.h>
#include <cstdint>
#include <cstddef>

// Problem dims (fixed)
constexpr int B_SZ = 64, IC = 2048, IH = 16, OC = 64, OH = 32;
constexpr int NN = OC * OH;          // 2048 flattened (o,j)
constexpr int ICHUNK = 32;           // i's per block
constexpr int NCHUNK = IC / ICHUNK;  // 64
constexpr int BTILE = 16;            // b's per block

typedef __attribute__((ext_vector_type(8))) short bf16x8;
typedef __attribute__((ext_vector_type(4))) float f32x4;

// ---- LDS layout (bytes), dynamic shared ----
constexpr int F_Z = 0;                        // 64 B zeros (K-pad A-frag)
constexpr int F_W = 64;                       // double-buffered W: 2 x 64 KiB
constexpr int F_WBUF = 65536;                 // [2 slot][2048 n][8 h] bf16 per i
constexpr int F_T = F_W + 2 * F_WBUF;         // 131136: denom partials, 2 bufs
constexpr int T_ROW = 80;                     // bytes per b-row (20 floats, 16 used)
constexpr int T_BUF = 16 * T_ROW;             // 1280 B
constexpr int F_SMEM = F_T + 2 * T_BUF;       // 133696 (< 160 KiB)

__device__ __forceinline__ unsigned short f2bf(float f) {
    unsigned u = __float_as_uint(f);
    u += 0x7fffu + ((u >> 16) & 1u);          // round-to-nearest-even
    return (unsigned short)(u >> 16);
}
__device__ __forceinline__ float bf_lo(unsigned u) {
    return __uint_as_float(u << 16);
}
__device__ __forceinline__ float bf_hi(unsigned u) {
    return __uint_as_float(u & 0xffff0000u);
}
__device__ __forceinline__ unsigned pk2f(float a, float b) {
    return (unsigned)f2bf(a) | ((unsigned)f2bf(b) << 16);
}
__device__ __forceinline__ void gload_lds16(const void* g, void* l) {
    __builtin_amdgcn_global_load_lds(
        (const __attribute__((address_space(1))) void*)g,
        (__attribute__((address_space(3))) void*)l, 16, 0, 0);
}

// Fused prep:
//   W fp32 [2048 i][16 h][2048 n] -> Wp bf16 [i][2 slot][2048 n][8 h]
//   x  f32 [64 b][2048 i][16 h]   -> xs bf16 [2048 i][64 b][16 h]   (threads 0..63)
__global__ void prep_wx(const float* __restrict__ W, unsigned short* __restrict__ Wp,
                        const float* __restrict__ x, unsigned short* __restrict__ xs) {
    int i = blockIdx.x;
    int t = threadIdx.x;            // 0..511, handles n = 4t..4t+3
    const float* wp = W + (size_t)i * (IH * NN);
    int n0 = t * 4;
    float4 row[16];
#pragma unroll
    for (int h = 0; h < 16; ++h) row[h] = *(const float4*)(wp + h * NN + n0);
    char* dst = (char*)Wp + (size_t)i * 65536;
#pragma unroll
    for (int q = 0; q < 4; ++q) {
        float v[16];
#pragma unroll
        for (int h = 0; h < 16; ++h) v[h] = ((const float*)&row[h])[q];
        uint4 lo, hi;
        lo.x = pk2f(v[0], v[1]);   lo.y = pk2f(v[2], v[3]);
        lo.z = pk2f(v[4], v[5]);   lo.w = pk2f(v[6], v[7]);
        hi.x = pk2f(v[8], v[9]);   hi.y = pk2f(v[10], v[11]);
        hi.z = pk2f(v[12], v[13]); hi.w = pk2f(v[14], v[15]);
        *(uint4*)(dst + (size_t)(n0 + q) * 16) = lo;
        *(uint4*)(dst + 32768 + (size_t)(n0 + q) * 16) = hi;
    }
    if (t < 64) {
        const float* p = x + ((size_t)t * IC + i) * IH;
        unsigned short out[16];
#pragma unroll
        for (int h = 0; h < 16; ++h) out[h] = f2bf(p[h]);
        unsigned short* q = xs + ((size_t)i * 64 + t) * 16;
        *(uint4*)q = *(uint4*)&out[0];
        *(uint4*)(q + 8) = *(uint4*)&out[8];
    }
}

// ---------------- routed pass: 16 waves, wave owns 4 o's ----------------
// One barrier per i. Stage(i+1) + xf(i+1) issued first; softmax has no max
// (range-safe) and no C round-trip: exp stays in registers, only the per-b
// denominator crosses waves via a tiny double-buffered LDS table.
template <bool UNIFORM>
__launch_bounds__(1024, 4)
__global__ void routed_fast(const unsigned short* __restrict__ xs,
                            const unsigned short* __restrict__ Wp,
                            const float* __restrict__ Vin,
                            float* __restrict__ P) {
    extern __shared__ char smem[];
    const int tid = threadIdx.x;
    const int lane = tid & 63;
    const int wv = tid >> 6;              // wave 0..15, owns o in [wv*4, wv*4+4)
    const int l15 = lane & 15;
    const int g = lane >> 4;              // lane group 0..3

    const int v = blockIdx.x;
    const int bt = (v >> 3) & 3;          // 4 b-tiles of a chunk share an XCD
    const int chunk = (v & 7) + 8 * (v >> 5);
    const int b0 = bt * BTILE;
    const int i0 = chunk * ICHUNK;

    if (tid < 16) ((unsigned*)(smem + F_Z))[tid] = 0u;

    // V is i-invariant: this lane needs 32 values (4 o x 8 j); pack to bf16.
    uint4 vrp[4];
    if constexpr (!UNIFORM) {
#pragma unroll
        for (int o8 = 0; o8 < 4; ++o8) {
            const float* vb =
                Vin + ((size_t)(b0 + l15) * OC + (wv * 4 + o8)) * OH + g * 4;
            f32x4 a = *(const f32x4*)vb;          // j = g*4..
            f32x4 c = *(const f32x4*)(vb + 16);   // j = 16+g*4..
            vrp[o8].x = pk2f(a.x, a.y);
            vrp[o8].y = pk2f(a.z, a.w);
            vrp[o8].z = pk2f(c.x, c.y);
            vrp[o8].w = pk2f(c.z, c.w);
        }
    }

    // prologue: stage i0 into buf0, load xf(i0)
    {
        const char* gs = (const char*)Wp + (size_t)i0 * 65536;
#pragma unroll
        for (int r = 0; r < 4; ++r) {
            int seg = r * 16 + wv;
            gload_lds16(gs + seg * 1024 + lane * 16, smem + F_W + seg * 1024);
        }
    }
    bf16x8 xf = {0, 0, 0, 0, 0, 0, 0, 0};
    if (lane < 32)
        xf = *(const bf16x8*)(xs + (size_t)i0 * 1024 + (size_t)(b0 + l15) * 16 + g * 8);
    asm volatile("s_waitcnt vmcnt(0) lgkmcnt(0)" ::: "memory");
    __builtin_amdgcn_s_barrier();

    const f32x4 fzero = {0.f, 0.f, 0.f, 0.f};
    f32x4 sacc[8];
#pragma unroll
    for (int t = 0; t < 8; ++t) sacc[t] = fzero;

    for (int ii = 0; ii < ICHUNK; ++ii) {
        const int cur = ii & 1;
        const char* wb = smem + F_W + cur * F_WBUF;
        const int i = i0 + ii;

        // ---- E: issue stage(i+1) + prefetch xf(i+1) first (max overlap) ----
        bf16x8 xf_n = {0, 0, 0, 0, 0, 0, 0, 0};
        if (ii + 1 < ICHUNK) {
            const char* gs = (const char*)Wp + (size_t)(i + 1) * 65536;
            char* lb = smem + F_W + (cur ^ 1) * F_WBUF;
#pragma unroll
            for (int r = 0; r < 4; ++r) {
                int seg = r * 16 + wv;
                gload_lds16(gs + seg * 1024 + lane * 16, lb + seg * 1024);
            }
            if (lane < 32)
                xf_n = *(const bf16x8*)(xs + (size_t)(i + 1) * 1024 +
                                        (size_t)(b0 + l15) * 16 + g * 8);
        }

        // ---- B: MFMA phase ----
        f32x4 acc[8];
#pragma unroll
        for (int t = 0; t < 8; ++t) {
            int nt = wv * 128 + (t >> 1) * 32 + (t & 1) * 16;
            const char* aptr = (lane < 32)
                ? (wb + g * 32768 + (size_t)(nt + l15) * 16)
                : (smem + F_Z);
            bf16x8 af = *(const bf16x8*)aptr;
            if constexpr (UNIFORM) {
                sacc[t] = __builtin_amdgcn_mfma_f32_16x16x32_bf16(af, xf, sacc[t], 0, 0, 0);
            } else {
                acc[t] = __builtin_amdgcn_mfma_f32_16x16x32_bf16(af, xf, fzero, 0, 0, 0);
            }
        }

        if constexpr (UNIFORM) {
            asm volatile("s_waitcnt vmcnt(0)" ::: "memory");
            __builtin_amdgcn_s_barrier();
        } else {
            // ---- C: Blog dots, reduce over g-groups, exp in-register ----
            float eb[4], s4;
#pragma unroll
            for (int o8 = 0; o8 < 4; ++o8) {
                f32x4 a0 = acc[2 * o8], a1 = acc[2 * o8 + 1];
                uint4 u = vrp[o8];
                float p = a0.x * bf_lo(u.x) + a0.y * bf_hi(u.x) +
                          a0.z * bf_lo(u.y) + a0.w * bf_hi(u.y) +
                          a1.x * bf_lo(u.z) + a1.y * bf_hi(u.z) +
                          a1.z * bf_lo(u.w) + a1.w * bf_hi(u.w);
                p += __shfl_xor(p, 16);
                p += __shfl_xor(p, 32);
                // p = Blog[b=l15][o=wv*4+o8]; no max subtraction (|Blog|<~12)
                eb[o8] = __expf(p);
            }
            s4 = (eb[0] + eb[1]) + (eb[2] + eb[3]);

            // ---- D: write this wave's per-b partial denom ----
            if (lane < 16)
                *(float*)(smem + F_T + cur * T_BUF + l15 * T_ROW + wv * 4) = s4;

            // ---- F: single barrier (T ready + W(i+1) landed) ----
            asm volatile("s_waitcnt vmcnt(0) lgkmcnt(0)" ::: "memory");
            __builtin_amdgcn_s_barrier();

            // ---- G: denominator from T row b=l15 (broadcast, 2-way max) ----
            const char* tb = smem + F_T + cur * T_BUF + l15 * T_ROW;
            f32x4 t0 = *(const f32x4*)(tb);
            f32x4 t1 = *(const f32x4*)(tb + 16);
            f32x4 t2 = *(const f32x4*)(tb + 32);
            f32x4 t3 = *(const f32x4*)(tb + 48);
            f32x4 ts = (t0 + t1) + (t2 + t3);
            float denom = (ts.x + ts.y) + (ts.z + ts.w);
            float rd = __builtin_amdgcn_rcpf(denom);
            float c0 = eb[0] * rd, c1 = eb[1] * rd, c2 = eb[2] * rd, c3 = eb[3] * rd;
#pragma unroll
            for (int t = 0; t < 8; ++t) {
                float c = (t < 2) ? c0 : (t < 4) ? c1 : (t < 6) ? c2 : c3;
                sacc[t] += acc[t] * c;
            }
        }
        xf = xf_n;
    }

    // ---- write partial S: P[chunk][b][n] ----
    const float scale = UNIFORM ? (1.0f / 64.0f) : 1.0f;
#pragma unroll
    for (int t = 0; t < 8; ++t) {
        int n = wv * 128 + (t >> 1) * 32 + (t & 1) * 16 + g * 4;
        float* dst = P + ((size_t)(chunk * 64) + b0 + l15) * NN + n;
        float4 o4;
        o4.x = sacc[t].x * scale; o4.y = sacc[t].y * scale;
        o4.z = sacc[t].z * scale; o4.w = sacc[t].w * scale;
        *(float4*)dst = o4;
    }
}

// Sum partials over chunks, squash over j, SET or ADD into dst.
__global__ void reduce_squash(const float* __restrict__ P, float* __restrict__ dst,
                              int addmode) {
    int pr = blockIdx.x * 2 + (threadIdx.x >> 5);  // (b,o) row 0..4095
    int j = threadIdx.x & 31;
    int b = pr >> 6, o = pr & 63;
    const float* p = P + (size_t)b * NN + o * 32 + j;
    float s = 0.f;
#pragma unroll 8
    for (int c = 0; c < NCHUNK; ++c) s += p[(size_t)c * (64 * NN)];
    float nsq = s * s;
#pragma unroll
    for (int d = 16; d >= 1; d >>= 1) nsq += __shfl_xor(nsq, d);
    float nrm = sqrtf(nsq);
    float f = nrm / (1.f + nsq);   // squash: x * ||x||/(1+||x||^2)
    float outv = s * f;
    int idx = pr * 32 + j;
    if (addmode) dst[idx] += outv;
    else dst[idx] = outv;
}

extern "C" void kernel_launch(void* const* d_in, const int* in_sizes, int n_in,
                              void* d_out, int out_size, void* d_ws, size_t ws_size,
                              hipStream_t stream) {
    const float* x = (const float*)d_in[0];   // [64][2048][16]
    const float* W = (const float*)d_in[1];   // [2048][16][64][32]
    float* out = (float*)d_out;               // [64][64][32]
    char* ws = (char*)d_ws;
    // ws: xs bf16 4 MiB | P f32 32 MiB @4M | Vsum 512 KiB @36M | Wp bf16 128 MiB @40M
    unsigned short* xs = (unsigned short*)ws;
    float* P = (float*)(ws + ((size_t)4 << 20));
    float* Vsum = (float*)(ws + ((size_t)36 << 20));
    unsigned short* Wp = (unsigned short*)(ws + (((size_t)40) << 20));

    (void)hipFuncSetAttribute(reinterpret_cast<const void*>(&routed_fast<true>),
                              hipFuncAttributeMaxDynamicSharedMemorySize, F_SMEM);
    (void)hipFuncSetAttribute(reinterpret_cast<const void*>(&routed_fast<false>),
                              hipFuncAttributeMaxDynamicSharedMemorySize, F_SMEM);

    prep_wx<<<dim3(2048), dim3(512), 0, stream>>>(W, Wp, x, xs);
    // iter 1: uniform C -> S1 -> V1 (Vsum = V1)
    routed_fast<true><<<dim3(256), dim3(1024), F_SMEM, stream>>>(xs, Wp, nullptr, P);
    reduce_squash<<<dim3(2048), dim3(64), 0, stream>>>(P, Vsum, 0);
    // iter 2: Blog = U.V1 -> S2 -> V2 (Vsum = V1+V2)
    routed_fast<false><<<dim3(256), dim3(1024), F_SMEM, stream>>>(xs, Wp, Vsum, P);
    reduce_squash<<<dim3(2048), dim3(64), 0, stream>>>(P, Vsum, 1);
    // iter 3: Blog = U.(V1+V2) -> S3 -> V3 = output
    routed_fast<false><<<dim3(256), dim3(1024), F_SMEM, stream>>>(xs, Wp, Vsum, P);
    reduce_squash<<<dim3(2048), dim3(64), 0, stream>>>(P, out, 0);
}